// Round 4
// baseline (1477.863 us; speedup 1.0000x reference)
//
#include <hip/hip_runtime.h>
#include <hip/hip_bf16.h>

#define DEPTH_T 11
#define HDIM 1024
#define VDIM 32001
#define NNODES 4095   // 2^12 - 1
#define LDV 32008     // padded bf16 logit row stride (x2B = 64016, 16B-aligned)

typedef __attribute__((ext_vector_type(8))) short bf16x8;
typedef __attribute__((ext_vector_type(8))) unsigned short ushort8;
typedef __attribute__((ext_vector_type(4))) float floatx4;

// Pre-order position of BFS/heap node m (0-based), perfect binary tree depth DEPTH_T.
__device__ __forceinline__ int preorder_pos(int m) {
    int q = m + 1;
    int d = 31 - __clz(q);
    int pos = 0;
    for (int i = 1; i <= d; ++i) {
        int b = (q >> (d - i)) & 1;
        pos += 1 + b * ((1 << (DEPTH_T - i + 1)) - 1);
    }
    return pos;
}

__device__ __forceinline__ float bf2f(unsigned short u) {
    return __uint_as_float(((unsigned)u) << 16);
}

#define BM 128
#define BN 128
#define BK 32

// C = A [M,K] @ Bt^T (Bt is [N,K] bf16 row-major) + bias[N]
// MODE 0: bf16 out = sigmoid(acc+bias)        MODE 1: bf16 out = acc+bias
// MODE 2: f32 out, rows scattered by preorder  MODE 3: bf16 out, rows scattered
template<int MODE, bool SWAPG>
__global__ __launch_bounds__(256, 2) void gemm_bt(
    const __hip_bfloat16* __restrict__ A,
    const __hip_bfloat16* __restrict__ Bt,
    const float* __restrict__ bias,
    void* __restrict__ outp,
    int M, int N, int K, int ldout)
{
    __shared__ __align__(16) __hip_bfloat16 As[BM][BK];
    __shared__ __align__(16) __hip_bfloat16 Bs[BN][BK];

    const int tid  = threadIdx.x;
    const int wave = tid >> 6;
    const int lane = tid & 63;
    const int m0 = (SWAPG ? blockIdx.x : blockIdx.y) * BM;
    const int n0 = (SWAPG ? blockIdx.y : blockIdx.x) * BN;
    const int wm = (wave & 1) * 64;
    const int wn = (wave >> 1) * 64;

    floatx4 acc[4][4];
#pragma unroll
    for (int i = 0; i < 4; ++i)
#pragma unroll
        for (int j = 0; j < 4; ++j) acc[i][j] = (floatx4)0.0f;

    const int lrow = lane >> 2;
    const int lcol = (lane & 3) * 8;
    const int fr = lane & 15;
    const int fk = (lane >> 4) * 8;

    for (int k0 = 0; k0 < K; k0 += BK) {
        __syncthreads();
#pragma unroll
        for (int t = 0; t < 2; ++t) {
            const int r = (wave * 2 + t) * 16;
            int gm = m0 + r + lrow; gm = gm < M ? gm : M - 1;
            const __hip_bfloat16* gp = A + (size_t)gm * K + (k0 + lcol);
            __builtin_amdgcn_global_load_lds(
                (const __attribute__((address_space(1))) void*)gp,
                (__attribute__((address_space(3))) void*)(&As[r][0]),
                16, 0, 0);
        }
#pragma unroll
        for (int t = 0; t < 2; ++t) {
            const int r = (wave * 2 + t) * 16;
            int gn = n0 + r + lrow; gn = gn < N ? gn : N - 1;
            const __hip_bfloat16* gp = Bt + (size_t)gn * K + (k0 + lcol);
            __builtin_amdgcn_global_load_lds(
                (const __attribute__((address_space(1))) void*)gp,
                (__attribute__((address_space(3))) void*)(&Bs[r][0]),
                16, 0, 0);
        }
        __syncthreads();

        bf16x8 af[4], bfv[4];
#pragma unroll
        for (int i = 0; i < 4; ++i)
            af[i] = *(const bf16x8*)(&As[wm + i * 16 + fr][fk]);
#pragma unroll
        for (int j = 0; j < 4; ++j)
            bfv[j] = *(const bf16x8*)(&Bs[wn + j * 16 + fr][fk]);
#pragma unroll
        for (int i = 0; i < 4; ++i)
#pragma unroll
            for (int j = 0; j < 4; ++j)
                acc[i][j] = __builtin_amdgcn_mfma_f32_16x16x32_bf16(
                    af[i], bfv[j], acc[i][j], 0, 0, 0);
    }

    const int rq = (lane >> 4) * 4;
    if (MODE >= 2) {
#pragma unroll
        for (int i = 0; i < 4; ++i) {
#pragma unroll
            for (int r = 0; r < 4; ++r) {
                const int gm = m0 + wm + i * 16 + rq + r;
                if (gm >= M) continue;
                const size_t orow = (size_t)preorder_pos(gm) * ldout;
#pragma unroll
                for (int j = 0; j < 4; ++j) {
                    const int gn = n0 + wn + j * 16 + fr;
                    if (gn < N) {
                        float v = acc[i][j][r] + bias[gn];
                        if (MODE == 2) ((float*)outp)[orow + gn] = v;
                        else ((__hip_bfloat16*)outp)[orow + gn] = __float2bfloat16(v);
                    }
                }
            }
        }
    } else {
        __hip_bfloat16* O = (__hip_bfloat16*)outp;
#pragma unroll
        for (int i = 0; i < 4; ++i) {
#pragma unroll
            for (int r = 0; r < 4; ++r) {
                const int gm = m0 + wm + i * 16 + rq + r;
                if (gm >= M) continue;
#pragma unroll
                for (int j = 0; j < 4; ++j) {
                    const int gn = n0 + wn + j * 16 + fr;
                    if (gn < N) {
                        float v = acc[i][j][r] + bias[gn];
                        if (MODE == 0) v = 1.0f / (1.0f + __expf(-v));
                        O[(size_t)gm * ldout + gn] = __float2bfloat16(v);
                    }
                }
            }
        }
    }
}

// ============================================================================
// 256x256 8-phase GEMM, v4: unit-level-verified schedule.
// KEY FACT the v2/v3 ledgers missed: a wave reads BOTH its ALO and AHI register
// batches from ONE staging unit (A-lo for wm=0 waves, A-hi for wm=128), and
// both BLO/BHI from one B unit. So unit read-liveness = last of the two reg
// batches, across all waves, certified by LGKM drain + exit barrier.
//
// Symmetric schedule, 4 phases/tile, reads one phase ahead (Gray Q-order):
//   P1: RD AHI0(8)        | M=Q1(alo,blo)  LGKM(8)
//   P2: RD BHI0(4)        | M=Q2(ahi,blo)  LGKM(4)
//   P3: stage buf0.A x2, VMC(4) | M=Q4(alo,bhi)  LGKM(0)
//   P4: RD ALO1+BLO1(12), stage buf0.B x2 | M=Q3(ahi,bhi)  LGKM(12)
//   P5-P8: mirror on buf1 (stage buf1.A @P7 +VMC(4), buf1.B @P8)
// WAR: buf0.A reads drained P2-LGKM(4)+BAR -> stage P3. buf0.B drained
// P3-LGKM(0)+BAR -> stage P4. buf1.A drained P6+BAR -> P7; buf1.B drained
// P7-LGKM(0)+BAR -> P8. RAW: buf1(t+1) staged P7/P8 prev, cert P3-VMC(4)+BAR
// before P4 reads; buf0(t+2) staged P3/P4, cert P7-VMC(4)+BAR before P8 reads.
// Stage->cert gaps 3-4 phases (> HBM latency). vmcnt FIFO counts verified
// incl. prologue (VMC(8) after 16 insts = buf0 landed; buf1 cert at P3).
// Register WAR: each phase's RD target batch is disjoint from its MFMA
// operands (Gray order), so C++ value semantics + compiler dep-tracking hold;
// SB0 after each LGKM pins MFMA (rule #18).
// Addressing/swizzle/epilogue identical to the R1-passing kernel.
// ============================================================================
#define B2M 256
#define B2N 256

template<int MODE>
__global__ __launch_bounds__(512, 2) void gemm256(
    const __hip_bfloat16* __restrict__ A,
    const __hip_bfloat16* __restrict__ Bt,
    const float* __restrict__ bias,
    void* __restrict__ outp,
    int M, int N, int K, int ldout)
{
    __shared__ __align__(16) char smem[131072];

    const int tid  = threadIdx.x;
    const int wave = tid >> 6;
    const int lane = tid & 63;

    const int nwx = (M + B2M - 1) / B2M;
    const int nwy = (N + B2N - 1) / B2N;
    const int nwg = nwx * nwy;
    int wg = blockIdx.x;
    if ((nwg & 7) == 0) wg = (wg & 7) * (nwg >> 3) + (wg >> 3);  // XCD chunk
    const int m0 = (wg % nwx) * B2M;
    const int n0 = (wg / nwx) * B2N;

    const int wm = (wave >> 2) * 128;   // 0 / 128
    const int wn = (wave & 3) * 64;     // 0 / 64 / 128 / 192
    const int nkt = K >> 6;             // # 64-wide K-tiles (even)

    // staging: per-lane pre-swizzled global source
    const int s_row = lane >> 3;                    // 0..7
    const int s_col = ((lane & 7) ^ s_row) * 8;     // bf16 col within 64-col slab

    // fragment read addressing (swizzled)
    const int fr  = lane & 15;
    const int fkq = lane >> 4;                      // 0..3
    const int swz = (fr & 7) << 4;
    const int c0  = (fkq * 16) ^ swz;               // ks=0 col-bytes
    const int c1  = (64 + fkq * 16) ^ swz;          // ks=1 col-bytes
    const int aoff = (wm + fr) * 128;
    const int boff = 32768 + (wn + fr) * 128;

    floatx4 acc[8][4];
#pragma unroll
    for (int i = 0; i < 8; ++i)
#pragma unroll
        for (int j = 0; j < 4; ++j) acc[i][j] = (floatx4)0.0f;

    bf16x8 alo[8], ahi[8], blo[4], bhi[4];

    auto stage = [&](int bsel, int mat, int h, int kt) {
        const int ktc = kt < nkt ? kt : 0;
        const __hip_bfloat16* gb = mat ? Bt : A;
        const int lim = mat ? N : M;
        const int g0  = mat ? n0 : m0;
#pragma unroll
        for (int inst = 0; inst < 2; ++inst) {
            const int rg = inst * 8 + wave;
            int gr = g0 + h * 128 + rg * 8 + s_row;
            gr = gr < lim ? gr : lim - 1;
            const __hip_bfloat16* gp = gb + (size_t)gr * K + (ktc * 64 + s_col);
            __builtin_amdgcn_global_load_lds(
                (const __attribute__((address_space(1))) void*)gp,
                (__attribute__((address_space(3))) void*)
                    (smem + bsel * 65536 + mat * 32768 + h * 16384 + rg * 1024),
                16, 0, 0);
        }
    };

#define RD_ALO(bsel) \
    _Pragma("unroll") \
    for (int f = 0; f < 4; ++f) { \
        alo[f*2+0] = *(const bf16x8*)(smem + (bsel)*65536 + aoff + f*2048 + c0); \
        alo[f*2+1] = *(const bf16x8*)(smem + (bsel)*65536 + aoff + f*2048 + c1); }
#define RD_AHI(bsel) \
    _Pragma("unroll") \
    for (int f = 0; f < 4; ++f) { \
        ahi[f*2+0] = *(const bf16x8*)(smem + (bsel)*65536 + aoff + (4+f)*2048 + c0); \
        ahi[f*2+1] = *(const bf16x8*)(smem + (bsel)*65536 + aoff + (4+f)*2048 + c1); }
#define RD_BLO(bsel) \
    _Pragma("unroll") \
    for (int j = 0; j < 2; ++j) { \
        blo[j*2+0] = *(const bf16x8*)(smem + (bsel)*65536 + boff + j*2048 + c0); \
        blo[j*2+1] = *(const bf16x8*)(smem + (bsel)*65536 + boff + j*2048 + c1); }
#define RD_BHI(bsel) \
    _Pragma("unroll") \
    for (int j = 0; j < 2; ++j) { \
        bhi[j*2+0] = *(const bf16x8*)(smem + (bsel)*65536 + boff + (2+j)*2048 + c0); \
        bhi[j*2+1] = *(const bf16x8*)(smem + (bsel)*65536 + boff + (2+j)*2048 + c1); }
// 16 MFMA: quadrant (IB: a-frag base 0/4, JB: b-frag base 0/2)
#define MM_Q(IB, JB, AA, BB) \
    _Pragma("unroll") \
    for (int f = 0; f < 4; ++f) \
    _Pragma("unroll") \
    for (int jj = 0; jj < 2; ++jj) \
    _Pragma("unroll") \
    for (int ks = 0; ks < 2; ++ks) \
        acc[(IB)+f][(JB)+jj] = __builtin_amdgcn_mfma_f32_16x16x32_bf16( \
            AA[f*2+ks], BB[jj*2+ks], acc[(IB)+f][(JB)+jj], 0, 0, 0);

#define VMC(n)  asm volatile("s_waitcnt vmcnt(" #n ")" ::: "memory")
#define LGKM(n) asm volatile("s_waitcnt lgkmcnt(" #n ")" ::: "memory")
#define SB0    __builtin_amdgcn_sched_barrier(0)
#define BAR    __builtin_amdgcn_s_barrier()
#define PRIO1  __builtin_amdgcn_s_setprio(1)
#define PRIO0  __builtin_amdgcn_s_setprio(0)

    // ---- prologue: buf0 <- t0 (8 insts), buf1 <- t1 (8 insts) ----
    stage(0, 0, 0, 0);  // buf0 A-lo
    stage(0, 0, 1, 0);  // buf0 A-hi
    stage(0, 1, 0, 0);  // buf0 B-lo
    stage(0, 1, 1, 0);  // buf0 B-hi
    stage(1, 0, 0, 1);  // buf1 A-lo
    stage(1, 0, 1, 1);  // buf1 A-hi
    stage(1, 1, 0, 1);  // buf1 B-lo
    stage(1, 1, 1, 1);  // buf1 B-hi
    VMC(8);             // buf0's 8 landed; buf1's 8 in flight (cert at P3)
    BAR;
    RD_ALO(0); RD_BLO(0);   // 12 reads for P1's Q1

#pragma unroll 1
    for (int t = 0; t < nkt; t += 2) {
        // P1: RD AHI0 | M=Q1(alo,blo buf0)
        RD_AHI(0);
        BAR;
        LGKM(8); SB0;
        PRIO1; MM_Q(0, 0, alo, blo); PRIO0;
        BAR;
        // P2: RD BHI0 | M=Q2(ahi,blo)
        RD_BHI(0);
        BAR;
        LGKM(4); SB0;
        PRIO1; MM_Q(4, 0, ahi, blo); PRIO0;
        BAR;
        // P3: stage buf0.A (t+2) [A reads drained P2+BAR] | cert buf1 | M=Q4(alo,bhi)
        stage(0, 0, 0, t + 2);
        stage(0, 0, 1, t + 2);
        VMC(4); BAR;
        LGKM(0); SB0;
        PRIO1; MM_Q(0, 2, alo, bhi); PRIO0;
        BAR;
        // P4: RD ALO1+BLO1 (buf1 cert'd P3) | stage buf0.B (t+2) [B reads drained P3+BAR] | M=Q3(ahi,bhi)
        RD_ALO(1); RD_BLO(1);
        stage(0, 1, 0, t + 2);
        stage(0, 1, 1, t + 2);
        BAR;
        LGKM(12); SB0;
        PRIO1; MM_Q(4, 2, ahi, bhi); PRIO0;
        BAR;
        // P5: RD AHI1 | M=Q1'(alo,blo buf1)
        RD_AHI(1);
        BAR;
        LGKM(8); SB0;
        PRIO1; MM_Q(0, 0, alo, blo); PRIO0;
        BAR;
        // P6: RD BHI1 | M=Q2'(ahi,blo)
        RD_BHI(1);
        BAR;
        LGKM(4); SB0;
        PRIO1; MM_Q(4, 0, ahi, blo); PRIO0;
        BAR;
        // P7: stage buf1.A (t+3) [drained P6+BAR] | cert buf0(t+2) | M=Q4'(alo,bhi)
        stage(1, 0, 0, t + 3);
        stage(1, 0, 1, t + 3);
        VMC(4); BAR;
        LGKM(0); SB0;
        PRIO1; MM_Q(0, 2, alo, bhi); PRIO0;
        BAR;
        // P8: RD ALO0+BLO0 (t+2, cert'd P7) | stage buf1.B (t+3) [drained P7+BAR] | M=Q3'(ahi,bhi)
        RD_ALO(0); RD_BLO(0);
        stage(1, 1, 0, t + 3);
        stage(1, 1, 1, t + 3);
        BAR;
        LGKM(12); SB0;
        PRIO1; MM_Q(4, 2, ahi, bhi); PRIO0;
        BAR;
    }

#undef RD_ALO
#undef RD_AHI
#undef RD_BLO
#undef RD_BHI
#undef MM_Q
#undef VMC
#undef LGKM
#undef SB0
#undef BAR
#undef PRIO1
#undef PRIO0

    // ---- epilogue: C/D layout col = lane&15, row = (lane>>4)*4 + reg ----
    const int rq = (lane >> 4) * 4;
    if (MODE >= 2) {
#pragma unroll
        for (int i = 0; i < 8; ++i) {
#pragma unroll
            for (int r = 0; r < 4; ++r) {
                const int gm = m0 + wm + i * 16 + rq + r;
                if (gm >= M) continue;
                const size_t orow = (size_t)preorder_pos(gm) * ldout;
#pragma unroll
                for (int j = 0; j < 4; ++j) {
                    const int gn = n0 + wn + j * 16 + fr;
                    if (gn < N) {
                        float v = acc[i][j][r] + bias[gn];
                        if (MODE == 2) ((float*)outp)[orow + gn] = v;
                        else ((__hip_bfloat16*)outp)[orow + gn] = __float2bfloat16(v);
                    }
                }
            }
        }
    } else {
        __hip_bfloat16* O = (__hip_bfloat16*)outp;
#pragma unroll
        for (int i = 0; i < 8; ++i) {
#pragma unroll
            for (int r = 0; r < 4; ++r) {
                const int gm = m0 + wm + i * 16 + rq + r;
                if (gm >= M) continue;
#pragma unroll
                for (int j = 0; j < 4; ++j) {
                    const int gn = n0 + wn + j * 16 + fr;
                    if (gn < N) {
                        float v = acc[i][j][r] + bias[gn];
                        if (MODE == 0) v = 1.0f / (1.0f + __expf(-v));
                        O[(size_t)gm * ldout + gn] = __float2bfloat16(v);
                    }
                }
            }
        }
    }
}

// Small-M GEMM: no LDS, no barriers — loads software-pipeline via vmcnt.
template<int MODE>
__global__ __launch_bounds__(256) void gemm_small(
    const __hip_bfloat16* __restrict__ A,
    const __hip_bfloat16* __restrict__ Bt,
    const float* __restrict__ bias,
    __hip_bfloat16* __restrict__ O,
    int M, int N, int K)
{
    const int wave = threadIdx.x >> 6, lane = threadIdx.x & 63;
    const int n0 = blockIdx.x * 64 + wave * 16;
    const int m0 = blockIdx.y * 16;
    const int fr = lane & 15, fk = (lane >> 4) * 8;

    int am = m0 + fr; am = am < M ? am : M - 1;
    const __hip_bfloat16* ap = A + (size_t)am * K + fk;
    const __hip_bfloat16* bp = Bt + (size_t)(n0 + fr) * K + fk;

    floatx4 acc = (floatx4)0.0f;
#pragma unroll 8
    for (int k0 = 0; k0 < K; k0 += 32) {
        bf16x8 av = *(const bf16x8*)(ap + k0);
        bf16x8 bv = *(const bf16x8*)(bp + k0);
        acc = __builtin_amdgcn_mfma_f32_16x16x32_bf16(av, bv, acc, 0, 0, 0);
    }

    const int rq = (lane >> 4) * 4;
    const int gn = n0 + fr;
    const float b = bias[gn];
#pragma unroll
    for (int r = 0; r < 4; ++r) {
        const int gm = m0 + rq + r;
        if (gm >= M) continue;
        float v = acc[r] + b;
        if (MODE == 0) v = 1.0f / (1.0f + __expf(-v));
        O[(size_t)gm * N + gn] = __float2bfloat16(v);
    }
}

// in [R,C] f32 row-major -> outT [C,R] bf16 row-major. 64x64 tiles.
__global__ __launch_bounds__(256) void transpose_to_bf16(
    const float* __restrict__ in, __hip_bfloat16* __restrict__ outT, int R, int C)
{
    __shared__ float tile[64][65];
    const int c0 = blockIdx.x * 64, r0 = blockIdx.y * 64;
    const int tx = threadIdx.x & 63, ty = threadIdx.x >> 6;
#pragma unroll
    for (int i = 0; i < 64; i += 4) {
        int r = r0 + ty + i, c = c0 + tx;
        tile[ty + i][tx] = (r < R && c < C) ? in[(size_t)r * C + c] : 0.0f;
    }
    __syncthreads();
#pragma unroll
    for (int i = 0; i < 64; i += 4) {
        int rr = c0 + ty + i, cc = r0 + tx;
        if (rr < C && cc < R) outT[(size_t)rr * R + cc] = __float2bfloat16(tile[tx][ty + i]);
    }
}

__global__ __launch_bounds__(256) void convert_root(
    const float* __restrict__ in, __hip_bfloat16* __restrict__ out)
{
    int i = blockIdx.x * 256 + threadIdx.x;
    if (i < HDIM) out[i] = __float2bfloat16(in[i]);
}

// Log-softmax over bf16 logit rows (stride LDV), writing fp32 rows (stride VDIM).
__global__ __launch_bounds__(256) void logsoftmax_bf16(
    const unsigned short* __restrict__ L, float* __restrict__ O)
{
    extern __shared__ char smem[];
    unsigned short* rb = (unsigned short*)smem;
    float* wred = (float*)(smem + 64016);
    const int tid = threadIdx.x, lane = tid & 63, wv = tid >> 6;
    const unsigned short* src = L + (size_t)blockIdx.x * LDV;

    float m = -3.0e38f;
    for (int j = tid * 8; j < 32000; j += 2048) {
        ushort8 u = *(const ushort8*)(src + j);
        *(ushort8*)(rb + j) = u;
#pragma unroll
        for (int t = 0; t < 8; ++t) m = fmaxf(m, bf2f(u[t]));
    }
    if (tid == 0) { unsigned short u = src[32000]; rb[32000] = u; m = fmaxf(m, bf2f(u)); }
#pragma unroll
    for (int off = 32; off; off >>= 1) m = fmaxf(m, __shfl_xor(m, off, 64));
    if (lane == 0) wred[wv] = m;
    __syncthreads();
    const float M4 = fmaxf(fmaxf(wred[0], wred[1]), fmaxf(wred[2], wred[3]));

    float s = 0.0f;
    for (int j = tid * 8; j < 32000; j += 2048) {
        ushort8 u = *(const ushort8*)(rb + j);
#pragma unroll
        for (int t = 0; t < 8; ++t) s += __expf(bf2f(u[t]) - M4);
    }
    if (tid == 0) s += __expf(bf2f(rb[32000]) - M4);
#pragma unroll
    for (int off = 32; off; off >>= 1) s += __shfl_xor(s, off, 64);
    if (lane == 0) wred[4 + wv] = s;
    __syncthreads();
    const float lse = M4 + __logf(wred[4] + wred[5] + wred[6] + wred[7]);

    float* dst = O + (size_t)blockIdx.x * VDIM;
    for (int j = tid * 8; j < 32000; j += 2048) {
        ushort8 u = *(const ushort8*)(rb + j);
#pragma unroll
        for (int t = 0; t < 8; ++t) dst[j + t] = bf2f(u[t]) - lse;
    }
    if (tid == 0) dst[32000] = bf2f(rb[32000]) - lse;
}

// Fallback: in-place fp32 log_softmax (used only if ws too small for bf16 logits).
__global__ __launch_bounds__(256) void logsoftmax_rows(float* __restrict__ O, int n)
{
    __shared__ float sm[256], ssum[256];
    const int tid = threadIdx.x;
    float* p = O + (size_t)blockIdx.x * n;
    float m = -3.0e38f, s = 0.0f;
    for (int j = tid; j < n; j += 256) {
        float x = p[j];
        float nm = fmaxf(m, x);
        s = s * __expf(m - nm) + __expf(x - nm);
        m = nm;
    }
    sm[tid] = m; ssum[tid] = s;
    __syncthreads();
    for (int off = 128; off > 0; off >>= 1) {
        if (tid < off) {
            float m2 = sm[tid + off], s2 = ssum[tid + off];
            float nm = fmaxf(sm[tid], m2);
            ssum[tid] = ssum[tid] * __expf(sm[tid] - nm) + s2 * __expf(m2 - nm);
            sm[tid] = nm;
        }
        __syncthreads();
    }
    const float lse = sm[0] + __logf(ssum[0]);
    for (int j = tid; j < n; j += 256) p[j] -= lse;
}

extern "C" void kernel_launch(void* const* d_in, const int* in_sizes, int n_in,
                              void* d_out, int out_size, void* d_ws, size_t ws_size,
                              hipStream_t stream)
{
    const float* root = (const float*)d_in[0];
    const float* W1v  = (const float*)d_in[1];   // [1024, 2048]
    const float* b1v  = (const float*)d_in[2];
    const float* W2v  = (const float*)d_in[3];   // [2048, 32001]
    const float* b2v  = (const float*)d_in[4];
    const float* W1c  = (const float*)d_in[5];   // [1024, 2048]
    const float* b1c  = (const float*)d_in[6];
    const float* W2c  = (const float*)d_in[7];   // [2048, 2048]
    const float* b2c  = (const float*)d_in[8];

    char* ws = (char*)d_ws;
    __hip_bfloat16* Hall = (__hip_bfloat16*)(ws + 0);             // 4095x1024 (8 MB rgn)
    __hip_bfloat16* X1   = (__hip_bfloat16*)(ws +   8388608ull);  // 4095x2048 (16 MB rgn)
    __hip_bfloat16* Tt   = (__hip_bfloat16*)(ws +  25165824ull);  // 1024x2048 (4 MB)
    __hip_bfloat16* W1vT = (__hip_bfloat16*)(ws +  29360128ull);  // 2048x1024 (4 MB)
    __hip_bfloat16* W1cT = (__hip_bfloat16*)(ws +  33554432ull);  // 2048x1024 (4 MB)
    __hip_bfloat16* W2cT = (__hip_bfloat16*)(ws +  37748736ull);  // 2048x2048 (8 MB)
    __hip_bfloat16* W2vT = (__hip_bfloat16*)(ws +  46137344ull);  // 32001x2048 (ends 177,213,440)
    __hip_bfloat16* Lb   = (__hip_bfloat16*)(ws + 177213440ull);  // 4095xLDV bf16 logits
    const bool bf16_logits = ws_size >= 177213440ull + (size_t)NNODES * LDV * 2;

    dim3 blk(256);

    transpose_to_bf16<<<dim3( 32, 16), blk, 0, stream>>>(W1v, W1vT, 1024, 2048);
    transpose_to_bf16<<<dim3(501, 32), blk, 0, stream>>>(W2v, W2vT, 2048, VDIM);
    transpose_to_bf16<<<dim3( 32, 16), blk, 0, stream>>>(W1c, W1cT, 1024, 2048);
    transpose_to_bf16<<<dim3( 32, 32), blk, 0, stream>>>(W2c, W2cT, 2048, 2048);
    convert_root<<<dim3(4), blk, 0, stream>>>(root, Hall);

    // Child phase: level d -> d+1.
    for (int d = 0; d < DEPTH_T; ++d) {
        const int Md = 1 << d;
        __hip_bfloat16* Hd = Hall + (size_t)(Md - 1) * HDIM;
        __hip_bfloat16* Hn = Hall + (size_t)((2 << d) - 1) * HDIM;
        if (Md <= 256) {
            dim3 g(32, (Md + 15) / 16);
            gemm_small<0><<<g, blk, 0, stream>>>(Hd, W1cT, b1c, Tt, Md, 2048, 1024);
            gemm_small<1><<<g, blk, 0, stream>>>(Tt, W2cT, b2c, Hn, Md, 2048, 2048);
        } else {
            dim3 g(16, Md / 128);
            gemm_bt<0, false><<<g, blk, 0, stream>>>(Hd, W1cT, b1c, Tt, Md, 2048, 1024, 2048);
            gemm_bt<1, false><<<g, blk, 0, stream>>>(Tt, W2cT, b2c, Hn, Md, 2048, 2048, 2048);
        }
    }

    // Value phase.
    gemm_bt<0, false><<<dim3(16, 32), blk, 0, stream>>>(Hall, W1vT, b1v, X1, NNODES, 2048, 1024, 2048);
    if (bf16_logits) {
        // 1-D grid, XCD-swizzled inside the kernel (16 x-tiles * 126 y-tiles)
        gemm256<3><<<dim3(16 * 126), dim3(512), 0, stream>>>(X1, W2vT, b2v, Lb, NNODES, VDIM, 2048, LDV);
        logsoftmax_bf16<<<dim3(NNODES), blk, 64048, stream>>>((const unsigned short*)Lb, (float*)d_out);
    } else {
        gemm_bt<2, true><<<dim3(32, 251), blk, 0, stream>>>(X1, W2vT, b2v, d_out, NNODES, VDIM, 2048, VDIM);
        logsoftmax_rows<<<dim3(NNODES), blk, 0, stream>>>((float*)d_out, VDIM);
    }
}